// Round 7
// baseline (444.486 us; speedup 1.0000x reference)
//
#include <hip/hip_runtime.h>
#include <math.h>

#define NB 64        // batch
#define IFD 1024     // in features
#define PP 128       // P (num keys)
#define PSD 2048     // PS0/PS1
#define PK 64        // PKEY
#define NFD 64       // NF
#define DELTAF 1e-6f

typedef __bf16 bf16x8 __attribute__((ext_vector_type(8)));
typedef float f32x4 __attribute__((ext_vector_type(4)));
typedef unsigned short ushort;

static __device__ __forceinline__ ushort f2bf(float f) {
    unsigned int u = __float_as_uint(f);
    u = (u + 0x7FFF + ((u >> 16) & 1)) >> 16;   // RTNE
    return (ushort)u;
}
static __device__ __forceinline__ unsigned int pack2bf(float a, float b) {
    return (unsigned int)f2bf(a) | ((unsigned int)f2bf(b) << 16);
}
static __device__ __forceinline__ bf16x8 ld8cvt(const float* p) {
    float a[8];
    __builtin_memcpy(a, p, 32);
    bf16x8 r;
    #pragma unroll
    for (int i = 0; i < 8; ++i) r[i] = (__bf16)a[i];
    return r;
}

// ---------------------------------------------------------------------------
// Kernel 1 (MFMA): ko[comp][m][n] = sum_k x[m][k] * W[n][k] + b[n]
// (R3-measured config — untouched for attribution.)
// ---------------------------------------------------------------------------
__global__ __launch_bounds__(64) void k_proj(
    const float* __restrict__ x,
    const float* __restrict__ Wu, const float* __restrict__ bu,
    const float* __restrict__ Wv, const float* __restrict__ bv,
    const float* __restrict__ Ws, const float* __restrict__ bs,
    float* __restrict__ ko)
{
    const int comp = blockIdx.y;
    const float* W    = comp == 0 ? Wu : (comp == 1 ? Wv : Ws);
    const float* bias = comp == 0 ? bu : (comp == 1 ? bv : bs);
    float* out = ko + (size_t)comp * NB * 4096;

    const int n0 = blockIdx.x * 64;
    const int l = threadIdx.x;
    const int lr = l & 15, lk8 = (l >> 4) * 8;

    f32x4 acc[4][4] = {};
    #pragma unroll 2
    for (int kk = 0; kk < IFD; kk += 32) {
        bf16x8 af[4], bw[4];
        #pragma unroll
        for (int fi = 0; fi < 4; ++fi)
            af[fi] = ld8cvt(&x[(size_t)(fi * 16 + lr) * IFD + kk + lk8]);
        #pragma unroll
        for (int fj = 0; fj < 4; ++fj)
            bw[fj] = ld8cvt(&W[(size_t)(n0 + fj * 16 + lr) * IFD + kk + lk8]);
        #pragma unroll
        for (int fi = 0; fi < 4; ++fi)
            #pragma unroll
            for (int fj = 0; fj < 4; ++fj)
                acc[fi][fj] = __builtin_amdgcn_mfma_f32_16x16x32_bf16(
                    af[fi], bw[fj], acc[fi][fj], 0, 0, 0);
    }
    const int rb = (l >> 4) * 4, cl = l & 15;
    #pragma unroll
    for (int fi = 0; fi < 4; ++fi)
        #pragma unroll
        for (int fj = 0; fj < 4; ++fj) {
            const int n = n0 + fj * 16 + cl;
            const float bv_ = bias[n];
            #pragma unroll
            for (int r = 0; r < 4; ++r)
                out[(size_t)(fi * 16 + rb + r) * 4096 + n] = acc[fi][fj][r] + bv_;
        }
}

// ---------------------------------------------------------------------------
// Kernel 2a: a_n[comp][p] = ||MK_p|| + DELTA.
// ---------------------------------------------------------------------------
__global__ void k_norms(const float* __restrict__ PMU, const float* __restrict__ PMV,
                        const float* __restrict__ PMS, float* __restrict__ a_n)
{
    const int comp = blockIdx.x;
    const float* PM = comp == 0 ? PMU : (comp == 1 ? PMV : PMS);
    const int stride = (comp == 2) ? (PK + 1) : (PK + PSD);
    const int p = threadIdx.x;
    const float* row = PM + (size_t)p * stride;
    float ss = 0.f;
    #pragma unroll
    for (int k = 0; k < PK; ++k) { float v = row[k]; ss += v * v; }
    a_n[comp * PP + p] = sqrtf(ss) + DELTAF;
}

// ---------------------------------------------------------------------------
// Kernel 2b (MFMA): theta + softmax (+ fused softplus-cumsum for comp 2).
// ---------------------------------------------------------------------------
__global__ __launch_bounds__(256) void k_theta(
    const float* __restrict__ ko,
    const float* __restrict__ PMU, const float* __restrict__ PMV,
    const float* __restrict__ PMS, const float* __restrict__ a_n,
    ushort* __restrict__ d16, float* __restrict__ sbuf)
{
    const int comp = blockIdx.y;
    const int g = blockIdx.x;            // batch
    const float* PM = comp == 0 ? PMU : (comp == 1 ? PMV : PMS);
    const int stride = (comp == 2) ? (PK + 1) : (PK + PSD);
    const float* kg = ko + ((size_t)comp * NB + g) * 4096;

    __shared__ float an_s[128], bn_s[64], mpS[128], vrow[64];
    const int t = threadIdx.x;
    if (t < 128) an_s[t] = a_n[comp * PP + t];
    if (t < 64) {
        float ss = 0.f;
        #pragma unroll
        for (int k = 0; k < PK; ++k) { float v = kg[t * PK + k]; ss += v * v; }
        bn_s[t] = sqrtf(ss) + DELTAF;
    }
    if (comp == 2 && t >= 128) mpS[t - 128] = PM[(size_t)(t - 128) * stride + PK];
    __syncthreads();

    const int w = t >> 6, l = t & 63;
    const int lr = l & 15, lk8 = (l >> 4) * 8;

    f32x4 acc[8] = {};
    #pragma unroll
    for (int kk = 0; kk < 2; ++kk) {
        bf16x8 af = ld8cvt(&kg[(size_t)(w * 16 + lr) * PK + kk * 32 + lk8]);
        #pragma unroll
        for (int fj = 0; fj < 8; ++fj) {
            bf16x8 bw = ld8cvt(&PM[(size_t)(fj * 16 + lr) * stride + kk * 32 + lk8]);
            acc[fj] = __builtin_amdgcn_mfma_f32_16x16x32_bf16(af, bw, acc[fj], 0, 0, 0);
        }
    }

    const int rb = (l >> 4) * 4, cl = l & 15;
    float dv[8][4];
    #pragma unroll
    for (int fj = 0; fj < 8; ++fj) {
        const float an_v = an_s[fj * 16 + cl];
        #pragma unroll
        for (int r = 0; r < 4; ++r)
            dv[fj][r] = acc[fj][r] / (64.f * bn_s[w * 16 + rb + r] * an_v + DELTAF);
    }
    #pragma unroll
    for (int r = 0; r < 4; ++r) {
        float m = dv[0][r];
        #pragma unroll
        for (int fj = 1; fj < 8; ++fj) m = fmaxf(m, dv[fj][r]);
        #pragma unroll
        for (int msk = 1; msk < 16; msk <<= 1) m = fmaxf(m, __shfl_xor(m, msk, 64));
        float s = 0.f;
        #pragma unroll
        for (int fj = 0; fj < 8; ++fj) { dv[fj][r] = expf(dv[fj][r] - m); s += dv[fj][r]; }
        #pragma unroll
        for (int msk = 1; msk < 16; msk <<= 1) s += __shfl_xor(s, msk, 64);
        const float inv = 1.f / s;
        #pragma unroll
        for (int fj = 0; fj < 8; ++fj) dv[fj][r] *= inv;
    }

    if (comp < 2) {
        ushort* drow = d16 + ((size_t)comp * 4096 + g * 64) * PP;
        #pragma unroll
        for (int fj = 0; fj < 8; ++fj)
            #pragma unroll
            for (int r = 0; r < 4; ++r)
                drow[(size_t)(w * 16 + rb + r) * PP + fj * 16 + cl] = f2bf(dv[fj][r]);
    } else {
        #pragma unroll
        for (int r = 0; r < 4; ++r) {
            float v = 0.f;
            #pragma unroll
            for (int fj = 0; fj < 8; ++fj) v += dv[fj][r] * mpS[fj * 16 + cl];
            #pragma unroll
            for (int msk = 1; msk < 16; msk <<= 1) v += __shfl_xor(v, msk, 64);
            if ((l & 15) == 0) vrow[w * 16 + rb + r] = v;
        }
        __syncthreads();
        if (t < 64) {
            float v = vrow[t];
            float sp = (v > 20.f) ? v : log1pf(expf(v));
            #pragma unroll
            for (int o = 1; o < 64; o <<= 1) {
                float u = __shfl_up(sp, o, 64);
                if (t >= o) sp += u;
            }
            sbuf[g * 64 + t] = sp;
        }
    }
}

// ---------------------------------------------------------------------------
// Kernel 3: transpose MP[:,PK:] -> MPt[comp][n][p] bf16.  (R3 config.)
// ---------------------------------------------------------------------------
__global__ __launch_bounds__(256) void k_mpt(
    const float* __restrict__ PMU, const float* __restrict__ PMV,
    ushort* __restrict__ MPt)
{
    const int comp = blockIdx.y;
    const float* PM = comp == 0 ? PMU : PMV;
    ushort* dst = MPt + (size_t)comp * PSD * PP;
    const int n0 = blockIdx.x * 64;
    __shared__ ushort Tl[64][136];
    const int t = threadIdx.x;
    const int nl = t & 63, p4 = t >> 6;
    #pragma unroll
    for (int it = 0; it < 32; ++it) {
        const int p = it * 4 + p4;
        Tl[nl][p] = f2bf(PM[(size_t)p * (PK + PSD) + PK + n0 + nl]);
    }
    __syncthreads();
    const int r = t >> 2, c = (t & 3) * 32;
    #pragma unroll
    for (int j = 0; j < 32; j += 8)
        *(f32x4*)&dst[(size_t)(n0 + r) * PP + c + j] = *(const f32x4*)&Tl[r][c + j];
}

// ---------------------------------------------------------------------------
// Kernel 4 (MFMA): Us/Vs = d16 @ MPt^T; Us scaled by s; output bf16 [b][n][f].
// ---------------------------------------------------------------------------
__global__ __launch_bounds__(256) void k_mp(
    const ushort* __restrict__ d16, const ushort* __restrict__ MPt,
    const float* __restrict__ sbuf,
    ushort* __restrict__ UsT, ushort* __restrict__ VsT)
{
    const int comp = blockIdx.z;
    const ushort* A = d16 + (size_t)comp * 4096 * PP;
    const ushort* B = MPt + (size_t)comp * PSD * PP;
    ushort* C = comp == 0 ? UsT : VsT;
    const int n0 = blockIdx.x * 128, m0 = blockIdx.y * 128;
    const int w = threadIdx.x >> 6, l = threadIdx.x & 63;
    const int wr = w >> 1, wc = w & 1;
    const int lr = l & 15, lk8 = (l >> 4) * 8;

    f32x4 acc[4][4] = {};
    #pragma unroll
    for (int kk = 0; kk < 4; ++kk) {
        bf16x8 af[4], bw[4];
        #pragma unroll
        for (int fi = 0; fi < 4; ++fi)
            af[fi] = *(const bf16x8*)&A[(size_t)(m0 + wr * 64 + fi * 16 + lr) * PP + kk * 32 + lk8];
        #pragma unroll
        for (int fj = 0; fj < 4; ++fj)
            bw[fj] = *(const bf16x8*)&B[(size_t)(n0 + wc * 64 + fj * 16 + lr) * PP + kk * 32 + lk8];
        #pragma unroll
        for (int fi = 0; fi < 4; ++fi)
            #pragma unroll
            for (int fj = 0; fj < 4; ++fj)
                acc[fi][fj] = __builtin_amdgcn_mfma_f32_16x16x32_bf16(
                    af[fi], bw[fj], acc[fi][fj], 0, 0, 0);
    }

    const int batch = (m0 >> 6) + wr;
    const int rb = (l >> 4) * 4, cl = l & 15;
    ushort* Cb = C + (size_t)batch * PSD * NFD;
    #pragma unroll
    for (int fi = 0; fi < 4; ++fi) {
        const int f0 = fi * 16 + rb;
        f32x4 sc;
        if (comp == 0) sc = *(const f32x4*)&sbuf[batch * 64 + f0];
        else           sc = (f32x4){1.f, 1.f, 1.f, 1.f};
        #pragma unroll
        for (int fj = 0; fj < 4; ++fj) {
            const int n = n0 + wc * 64 + fj * 16 + cl;
            uint2 pk;
            pk.x = pack2bf(acc[fi][fj][0] * sc[0], acc[fi][fj][1] * sc[1]);
            pk.y = pack2bf(acc[fi][fj][2] * sc[2], acc[fi][fj][3] * sc[3]);
            *(uint2*)&Cb[(size_t)n * NFD + f0] = pk;
        }
    }
}

// ---------------------------------------------------------------------------
// Kernel 5 (MFMA): Wrec[b] = Us[b]^T @ Vs[b].  16x2048 tile per block.
// R6 structure (LDS bounce -> wave-contiguous dwordx4 stores; XCD batch-chunk
// swizzle) with ONE change: PLAIN cached stores instead of nontemporal.
// Rationale: fill kernel proves plain dwordx4 through L2 sustains 6.6 TB/s;
// NT capped us at ~3.8 TB/s across three store patterns (R3/R5/R6).
// Full-line contiguous writes -> clean L2 evictions; panels L3-resident.
// grid 8192 linear, block 512 = 8 waves.
// ---------------------------------------------------------------------------
__global__ __launch_bounds__(512) void k_wrec(
    const ushort* __restrict__ UsT, const ushort* __restrict__ VsT,
    float* __restrict__ out)
{
    const int lin = blockIdx.x;
    const int nl2 = (lin & 7) * 1024 + (lin >> 3);   // bijective (8192 % 8 == 0)
    const int b = nl2 >> 7;
    const int i0 = (nl2 & 127) * 16;

    const int w = threadIdx.x >> 6, l = threadIdx.x & 63;
    const int j0 = w * 256;
    const int lr = l & 15, lk8 = (l >> 4) * 8;
    const ushort* A  = UsT + (size_t)b * PSD * NFD;
    const ushort* Bp = VsT + (size_t)b * PSD * NFD;

    // Transposed mfma(bw, af): lane (l&15) = output row, (l>>4)*4+reg = cols.
    f32x4 acc[16] = {};
    #pragma unroll
    for (int kk = 0; kk < 2; ++kk) {
        bf16x8 af = *(const bf16x8*)&A[(size_t)(i0 + lr) * NFD + kk * 32 + lk8];
        #pragma unroll
        for (int fj = 0; fj < 16; ++fj) {
            bf16x8 bw = *(const bf16x8*)&Bp[(size_t)(j0 + fj * 16 + lr) * NFD + kk * 32 + lk8];
            acc[fj] = __builtin_amdgcn_mfma_f32_16x16x32_bf16(bw, af, acc[fj], 0, 0, 0);
        }
    }

    __shared__ float lds[16 * 1024];    // 64 KB: 16 rows x 1024 cols (one half)
    const int cl = l & 15, rbq = l >> 4;
    float* ob = out + (size_t)b * (size_t)PSD * PSD + (size_t)i0 * PSD;

    #pragma unroll
    for (int h = 0; h < 2; ++h) {
        if ((w >> 2) == h) {            // waves owning this col-half write it
            const int cb0 = (w & 3) * 256 + rbq * 4;
            #pragma unroll
            for (int fj = 0; fj < 16; ++fj) {
                const int colbase = cb0 + fj * 16;
                *(f32x4*)&lds[cl * 1024 + (colbase ^ ((cl & 7) << 2))] = acc[fj];
            }
        }
        __syncthreads();
        const int r = 2 * w + (l >> 5);           // wave w -> rows 2w, 2w+1
        const int swz = (r & 7) << 2;
        #pragma unroll
        for (int inst = 0; inst < 8; ++inst) {
            const int c = (l & 31) * 4 + inst * 128;
            f32x4 v = *(const f32x4*)&lds[r * 1024 + (c ^ swz)];
            *(f32x4*)&ob[(size_t)r * PSD + h * 1024 + c] = v;
        }
        __syncthreads();
    }
}

// ---------------------------------------------------------------------------
extern "C" void kernel_launch(void* const* d_in, const int* in_sizes, int n_in,
                              void* d_out, int out_size, void* d_ws, size_t ws_size,
                              hipStream_t stream)
{
    const float* x   = (const float*)d_in[0];
    const float* PMU = (const float*)d_in[1];
    const float* PMV = (const float*)d_in[2];
    const float* PMS = (const float*)d_in[3];
    const float* Wku = (const float*)d_in[4];
    const float* bku = (const float*)d_in[5];
    const float* Wkv = (const float*)d_in[6];
    const float* bkv = (const float*)d_in[7];
    const float* Wks = (const float*)d_in[8];
    const float* bks = (const float*)d_in[9];
    float* out = (float*)d_out;

    char* ws = (char*)d_ws;
    float*  ko   = (float*)(ws);                                 // 3 MiB
    ushort* d16  = (ushort*)(ws + (size_t)3 * 1024 * 1024);      // 2 MiB
    ushort* MPt  = (ushort*)(ws + (size_t)5 * 1024 * 1024);      // 1 MiB
    float*  sbuf = (float*)(ws + (size_t)6 * 1024 * 1024);       // 16 KiB
    float*  a_n  = (float*)(ws + (size_t)6 * 1024 * 1024 + 65536);
    ushort* UsT  = (ushort*)(ws + (size_t)8 * 1024 * 1024);      // 16 MiB
    ushort* VsT  = (ushort*)(ws + (size_t)24 * 1024 * 1024);     // 16 MiB

    k_proj <<<dim3(64, 3),     64, 0, stream>>>(x, Wku, bku, Wkv, bkv, Wks, bks, ko);
    k_norms<<<3,              128, 0, stream>>>(PMU, PMV, PMS, a_n);
    k_mpt  <<<dim3(32, 2),    256, 0, stream>>>(PMU, PMV, MPt);
    k_theta<<<dim3(64, 3),    256, 0, stream>>>(ko, PMU, PMV, PMS, a_n, d16, sbuf);
    k_mp   <<<dim3(16, 32, 2),256, 0, stream>>>(d16, MPt, sbuf, UsT, VsT);
    k_wrec <<<8192,           512, 0, stream>>>(UsT, VsT, out);
}

// Round 8
// 368.091 us; speedup vs baseline: 1.2075x; 1.2075x over previous
//
#include <hip/hip_runtime.h>
#include <math.h>

#define NB 64        // batch
#define IFD 1024     // in features
#define PP 128       // P (num keys)
#define PSD 2048     // PS0/PS1
#define PK 64        // PKEY
#define NFD 64       // NF
#define DELTAF 1e-6f

typedef __bf16 bf16x8 __attribute__((ext_vector_type(8)));
typedef float f32x4 __attribute__((ext_vector_type(4)));
typedef unsigned short ushort;

static __device__ __forceinline__ ushort f2bf(float f) {
    unsigned int u = __float_as_uint(f);
    u = (u + 0x7FFF + ((u >> 16) & 1)) >> 16;   // RTNE
    return (ushort)u;
}
static __device__ __forceinline__ unsigned int pack2bf(float a, float b) {
    return (unsigned int)f2bf(a) | ((unsigned int)f2bf(b) << 16);
}
static __device__ __forceinline__ bf16x8 ld8cvt(const float* p) {
    float a[8];
    __builtin_memcpy(a, p, 32);
    bf16x8 r;
    #pragma unroll
    for (int i = 0; i < 8; ++i) r[i] = (__bf16)a[i];
    return r;
}

// ---------------------------------------------------------------------------
// Kernel 1 (MFMA) v3: ko[comp][m][n] = sum_k x[m][k]*W[n][k] + b[n]
// M=64, N=4096, K=1024.  grid (256 n-tiles of 16, 3), block 64 (1 wave).
// 768 waves (3/CU) + 4-deep K unroll -> enough outstanding HBM loads for the
// 48 MB W stream.  Same per-output kk accumulation chain as R3-R6 config ->
// bit-identical output (absmax must stay 4.882812e-4).
// ---------------------------------------------------------------------------
__global__ __launch_bounds__(64) void k_proj(
    const float* __restrict__ x,
    const float* __restrict__ Wu, const float* __restrict__ bu,
    const float* __restrict__ Wv, const float* __restrict__ bv,
    const float* __restrict__ Ws, const float* __restrict__ bs,
    float* __restrict__ ko)
{
    const int comp = blockIdx.y;
    const float* W    = comp == 0 ? Wu : (comp == 1 ? Wv : Ws);
    const float* bias = comp == 0 ? bu : (comp == 1 ? bv : bs);
    float* out = ko + (size_t)comp * NB * 4096;

    const int n0 = blockIdx.x * 16;
    const int l = threadIdx.x;
    const int lr = l & 15, lk8 = (l >> 4) * 8;

    f32x4 acc[4] = {};
    #pragma unroll 4
    for (int kk = 0; kk < IFD; kk += 32) {
        bf16x8 bw = ld8cvt(&W[(size_t)(n0 + lr) * IFD + kk + lk8]);
        #pragma unroll
        for (int fi = 0; fi < 4; ++fi) {
            bf16x8 af = ld8cvt(&x[(size_t)(fi * 16 + lr) * IFD + kk + lk8]);
            acc[fi] = __builtin_amdgcn_mfma_f32_16x16x32_bf16(af, bw, acc[fi], 0, 0, 0);
        }
    }
    const int rb = (l >> 4) * 4, cl = l & 15;
    const int n = n0 + cl;
    const float bv_ = bias[n];
    #pragma unroll
    for (int fi = 0; fi < 4; ++fi)
        #pragma unroll
        for (int r = 0; r < 4; ++r)
            out[(size_t)(fi * 16 + rb + r) * 4096 + n] = acc[fi][r] + bv_;
}

// ---------------------------------------------------------------------------
// Kernel 2a: a_n[comp][p] = ||MK_p|| + DELTA.
// ---------------------------------------------------------------------------
__global__ void k_norms(const float* __restrict__ PMU, const float* __restrict__ PMV,
                        const float* __restrict__ PMS, float* __restrict__ a_n)
{
    const int comp = blockIdx.x;
    const float* PM = comp == 0 ? PMU : (comp == 1 ? PMV : PMS);
    const int stride = (comp == 2) ? (PK + 1) : (PK + PSD);
    const int p = threadIdx.x;
    const float* row = PM + (size_t)p * stride;
    float ss = 0.f;
    #pragma unroll
    for (int k = 0; k < PK; ++k) { float v = row[k]; ss += v * v; }
    a_n[comp * PP + p] = sqrtf(ss) + DELTAF;
}

// ---------------------------------------------------------------------------
// Kernel 2b (MFMA): theta + softmax (+ fused softplus-cumsum for comp 2).
// (Unchanged.)
// ---------------------------------------------------------------------------
__global__ __launch_bounds__(256) void k_theta(
    const float* __restrict__ ko,
    const float* __restrict__ PMU, const float* __restrict__ PMV,
    const float* __restrict__ PMS, const float* __restrict__ a_n,
    ushort* __restrict__ d16, float* __restrict__ sbuf)
{
    const int comp = blockIdx.y;
    const int g = blockIdx.x;            // batch
    const float* PM = comp == 0 ? PMU : (comp == 1 ? PMV : PMS);
    const int stride = (comp == 2) ? (PK + 1) : (PK + PSD);
    const float* kg = ko + ((size_t)comp * NB + g) * 4096;

    __shared__ float an_s[128], bn_s[64], mpS[128], vrow[64];
    const int t = threadIdx.x;
    if (t < 128) an_s[t] = a_n[comp * PP + t];
    if (t < 64) {
        float ss = 0.f;
        #pragma unroll
        for (int k = 0; k < PK; ++k) { float v = kg[t * PK + k]; ss += v * v; }
        bn_s[t] = sqrtf(ss) + DELTAF;
    }
    if (comp == 2 && t >= 128) mpS[t - 128] = PM[(size_t)(t - 128) * stride + PK];
    __syncthreads();

    const int w = t >> 6, l = t & 63;
    const int lr = l & 15, lk8 = (l >> 4) * 8;

    f32x4 acc[8] = {};
    #pragma unroll
    for (int kk = 0; kk < 2; ++kk) {
        bf16x8 af = ld8cvt(&kg[(size_t)(w * 16 + lr) * PK + kk * 32 + lk8]);
        #pragma unroll
        for (int fj = 0; fj < 8; ++fj) {
            bf16x8 bw = ld8cvt(&PM[(size_t)(fj * 16 + lr) * stride + kk * 32 + lk8]);
            acc[fj] = __builtin_amdgcn_mfma_f32_16x16x32_bf16(af, bw, acc[fj], 0, 0, 0);
        }
    }

    const int rb = (l >> 4) * 4, cl = l & 15;
    float dv[8][4];
    #pragma unroll
    for (int fj = 0; fj < 8; ++fj) {
        const float an_v = an_s[fj * 16 + cl];
        #pragma unroll
        for (int r = 0; r < 4; ++r)
            dv[fj][r] = acc[fj][r] / (64.f * bn_s[w * 16 + rb + r] * an_v + DELTAF);
    }
    #pragma unroll
    for (int r = 0; r < 4; ++r) {
        float m = dv[0][r];
        #pragma unroll
        for (int fj = 1; fj < 8; ++fj) m = fmaxf(m, dv[fj][r]);
        #pragma unroll
        for (int msk = 1; msk < 16; msk <<= 1) m = fmaxf(m, __shfl_xor(m, msk, 64));
        float s = 0.f;
        #pragma unroll
        for (int fj = 0; fj < 8; ++fj) { dv[fj][r] = expf(dv[fj][r] - m); s += dv[fj][r]; }
        #pragma unroll
        for (int msk = 1; msk < 16; msk <<= 1) s += __shfl_xor(s, msk, 64);
        const float inv = 1.f / s;
        #pragma unroll
        for (int fj = 0; fj < 8; ++fj) dv[fj][r] *= inv;
    }

    if (comp < 2) {
        ushort* drow = d16 + ((size_t)comp * 4096 + g * 64) * PP;
        #pragma unroll
        for (int fj = 0; fj < 8; ++fj)
            #pragma unroll
            for (int r = 0; r < 4; ++r)
                drow[(size_t)(w * 16 + rb + r) * PP + fj * 16 + cl] = f2bf(dv[fj][r]);
    } else {
        #pragma unroll
        for (int r = 0; r < 4; ++r) {
            float v = 0.f;
            #pragma unroll
            for (int fj = 0; fj < 8; ++fj) v += dv[fj][r] * mpS[fj * 16 + cl];
            #pragma unroll
            for (int msk = 1; msk < 16; msk <<= 1) v += __shfl_xor(v, msk, 64);
            if ((l & 15) == 0) vrow[w * 16 + rb + r] = v;
        }
        __syncthreads();
        if (t < 64) {
            float v = vrow[t];
            float sp = (v > 20.f) ? v : log1pf(expf(v));
            #pragma unroll
            for (int o = 1; o < 64; o <<= 1) {
                float u = __shfl_up(sp, o, 64);
                if (t >= o) sp += u;
            }
            sbuf[g * 64 + t] = sp;
        }
    }
}

// ---------------------------------------------------------------------------
// Kernel 3 v2: transpose MP[:,PK:] -> MPt[comp][n][p] bf16.
// grid (32 n-tiles, 4 p-tiles, 2 comps) = 256 blocks; 8 reads/thread instead
// of 32 -> shorter dependent chains, 4x block-level parallelism.
// ---------------------------------------------------------------------------
__global__ __launch_bounds__(256) void k_mpt(
    const float* __restrict__ PMU, const float* __restrict__ PMV,
    ushort* __restrict__ MPt)
{
    const int comp = blockIdx.z;
    const float* PM = comp == 0 ? PMU : PMV;
    ushort* dst = MPt + (size_t)comp * PSD * PP;
    const int n0 = blockIdx.x * 64;
    const int p0 = blockIdx.y * 32;
    __shared__ ushort Tl[64][40];    // row stride 80 B (16B-aligned)
    const int t = threadIdx.x;
    const int nl = t & 63, pq = t >> 6;
    #pragma unroll
    for (int it = 0; it < 8; ++it) {
        const int pp = pq * 8 + it;
        Tl[nl][pp] = f2bf(PM[(size_t)(p0 + pp) * (PK + PSD) + PK + n0 + nl]);
    }
    __syncthreads();
    const int r = t >> 2, c = (t & 3) * 8;
    *(f32x4*)&dst[(size_t)(n0 + r) * PP + p0 + c] = *(const f32x4*)&Tl[r][c];
}

// ---------------------------------------------------------------------------
// Kernel 4 (MFMA): Us/Vs = d16 @ MPt^T; Us scaled by s; output bf16 [b][n][f].
// (Unchanged.)
// ---------------------------------------------------------------------------
__global__ __launch_bounds__(256) void k_mp(
    const ushort* __restrict__ d16, const ushort* __restrict__ MPt,
    const float* __restrict__ sbuf,
    ushort* __restrict__ UsT, ushort* __restrict__ VsT)
{
    const int comp = blockIdx.z;
    const ushort* A = d16 + (size_t)comp * 4096 * PP;
    const ushort* B = MPt + (size_t)comp * PSD * PP;
    ushort* C = comp == 0 ? UsT : VsT;
    const int n0 = blockIdx.x * 128, m0 = blockIdx.y * 128;
    const int w = threadIdx.x >> 6, l = threadIdx.x & 63;
    const int wr = w >> 1, wc = w & 1;
    const int lr = l & 15, lk8 = (l >> 4) * 8;

    f32x4 acc[4][4] = {};
    #pragma unroll
    for (int kk = 0; kk < 4; ++kk) {
        bf16x8 af[4], bw[4];
        #pragma unroll
        for (int fi = 0; fi < 4; ++fi)
            af[fi] = *(const bf16x8*)&A[(size_t)(m0 + wr * 64 + fi * 16 + lr) * PP + kk * 32 + lk8];
        #pragma unroll
        for (int fj = 0; fj < 4; ++fj)
            bw[fj] = *(const bf16x8*)&B[(size_t)(n0 + wc * 64 + fj * 16 + lr) * PP + kk * 32 + lk8];
        #pragma unroll
        for (int fi = 0; fi < 4; ++fi)
            #pragma unroll
            for (int fj = 0; fj < 4; ++fj)
                acc[fi][fj] = __builtin_amdgcn_mfma_f32_16x16x32_bf16(
                    af[fi], bw[fj], acc[fi][fj], 0, 0, 0);
    }

    const int batch = (m0 >> 6) + wr;
    const int rb = (l >> 4) * 4, cl = l & 15;
    ushort* Cb = C + (size_t)batch * PSD * NFD;
    #pragma unroll
    for (int fi = 0; fi < 4; ++fi) {
        const int f0 = fi * 16 + rb;
        f32x4 sc;
        if (comp == 0) sc = *(const f32x4*)&sbuf[batch * 64 + f0];
        else           sc = (f32x4){1.f, 1.f, 1.f, 1.f};
        #pragma unroll
        for (int fj = 0; fj < 4; ++fj) {
            const int n = n0 + wc * 64 + fj * 16 + cl;
            uint2 pk;
            pk.x = pack2bf(acc[fi][fj][0] * sc[0], acc[fi][fj][1] * sc[1]);
            pk.y = pack2bf(acc[fi][fj][2] * sc[2], acc[fi][fj][3] * sc[3]);
            *(uint2*)&Cb[(size_t)n * NFD + f0] = pk;
        }
    }
}

// ---------------------------------------------------------------------------
// Kernel 5 (MFMA): Wrec[b] = Us[b]^T @ Vs[b].  BYTE-IDENTICAL to R6 (best
// measured: NT + LDS bounce + XCD swizzle, ~3.8 TB/s NT-path cap).
// ---------------------------------------------------------------------------
__global__ __launch_bounds__(512) void k_wrec(
    const ushort* __restrict__ UsT, const ushort* __restrict__ VsT,
    float* __restrict__ out)
{
    const int lin = blockIdx.x;
    const int nl2 = (lin & 7) * 1024 + (lin >> 3);   // bijective (8192 % 8 == 0)
    const int b = nl2 >> 7;
    const int i0 = (nl2 & 127) * 16;

    const int w = threadIdx.x >> 6, l = threadIdx.x & 63;
    const int j0 = w * 256;
    const int lr = l & 15, lk8 = (l >> 4) * 8;
    const ushort* A  = UsT + (size_t)b * PSD * NFD;
    const ushort* Bp = VsT + (size_t)b * PSD * NFD;

    // Transposed mfma(bw, af): lane (l&15) = output row, (l>>4)*4+reg = cols.
    f32x4 acc[16] = {};
    #pragma unroll
    for (int kk = 0; kk < 2; ++kk) {
        bf16x8 af = *(const bf16x8*)&A[(size_t)(i0 + lr) * NFD + kk * 32 + lk8];
        #pragma unroll
        for (int fj = 0; fj < 16; ++fj) {
            bf16x8 bw = *(const bf16x8*)&Bp[(size_t)(j0 + fj * 16 + lr) * NFD + kk * 32 + lk8];
            acc[fj] = __builtin_amdgcn_mfma_f32_16x16x32_bf16(bw, af, acc[fj], 0, 0, 0);
        }
    }

    __shared__ float lds[16 * 1024];    // 64 KB: 16 rows x 1024 cols (one half)
    const int cl = l & 15, rbq = l >> 4;
    float* ob = out + (size_t)b * (size_t)PSD * PSD + (size_t)i0 * PSD;

    #pragma unroll
    for (int h = 0; h < 2; ++h) {
        if ((w >> 2) == h) {            // waves owning this col-half write it
            const int cb0 = (w & 3) * 256 + rbq * 4;
            #pragma unroll
            for (int fj = 0; fj < 16; ++fj) {
                const int colbase = cb0 + fj * 16;
                *(f32x4*)&lds[cl * 1024 + (colbase ^ ((cl & 7) << 2))] = acc[fj];
            }
        }
        __syncthreads();
        const int r = 2 * w + (l >> 5);           // wave w -> rows 2w, 2w+1
        const int swz = (r & 7) << 2;
        #pragma unroll
        for (int inst = 0; inst < 8; ++inst) {
            const int c = (l & 31) * 4 + inst * 128;
            f32x4 v = *(const f32x4*)&lds[r * 1024 + (c ^ swz)];
            __builtin_nontemporal_store(v, (f32x4*)&ob[(size_t)r * PSD + h * 1024 + c]);
        }
        __syncthreads();
    }
}

// ---------------------------------------------------------------------------
extern "C" void kernel_launch(void* const* d_in, const int* in_sizes, int n_in,
                              void* d_out, int out_size, void* d_ws, size_t ws_size,
                              hipStream_t stream)
{
    const float* x   = (const float*)d_in[0];
    const float* PMU = (const float*)d_in[1];
    const float* PMV = (const float*)d_in[2];
    const float* PMS = (const float*)d_in[3];
    const float* Wku = (const float*)d_in[4];
    const float* bku = (const float*)d_in[5];
    const float* Wkv = (const float*)d_in[6];
    const float* bkv = (const float*)d_in[7];
    const float* Wks = (const float*)d_in[8];
    const float* bks = (const float*)d_in[9];
    float* out = (float*)d_out;

    char* ws = (char*)d_ws;
    float*  ko   = (float*)(ws);                                 // 3 MiB
    ushort* d16  = (ushort*)(ws + (size_t)3 * 1024 * 1024);      // 2 MiB
    ushort* MPt  = (ushort*)(ws + (size_t)5 * 1024 * 1024);      // 1 MiB
    float*  sbuf = (float*)(ws + (size_t)6 * 1024 * 1024);       // 16 KiB
    float*  a_n  = (float*)(ws + (size_t)6 * 1024 * 1024 + 65536);
    ushort* UsT  = (ushort*)(ws + (size_t)8 * 1024 * 1024);      // 16 MiB
    ushort* VsT  = (ushort*)(ws + (size_t)24 * 1024 * 1024);     // 16 MiB

    k_proj <<<dim3(256, 3),    64, 0, stream>>>(x, Wku, bku, Wkv, bkv, Wks, bks, ko);
    k_norms<<<3,              128, 0, stream>>>(PMU, PMV, PMS, a_n);
    k_mpt  <<<dim3(32, 4, 2), 256, 0, stream>>>(PMU, PMV, MPt);
    k_theta<<<dim3(64, 3),    256, 0, stream>>>(ko, PMU, PMV, PMS, a_n, d16, sbuf);
    k_mp   <<<dim3(16, 32, 2),256, 0, stream>>>(d16, MPt, sbuf, UsT, VsT);
    k_wrec <<<8192,           512, 0, stream>>>(UsT, VsT, out);
}